// Round 2
// baseline (97.050 us; speedup 1.0000x reference)
//
#include <hip/hip_runtime.h>

// Problem constants (B=128, H=W=384)
#define ROWS 128
#define NCOL 147456              // 384*384
#define BPR  16                  // blocks per row
#define TPB  256
#define CHUNK (NCOL / BPR)       // 9216 floats per block
#define N4    (CHUNK / 4)        // 2304 float4 per block
#define ITERS (N4 / TPB)         // 9 float4 per thread per array
#define NBLK  (ROWS * BPR)       // 2048 blocks
static constexpr long long K0 = 117964;  // int((1.0 - 0.2) * NCOL)

// Single fused kernel: per-block partial {sum(res), count(valid)} -> ws;
// last block (fence+atomic) combines partials, handles the (never-hit-here)
// general trim case via radix select, and writes the mean loss.
__global__ __launch_bounds__(TPB, 4) void fused_kernel(
    const float* __restrict__ pred, const float* __restrict__ tgt,
    float* __restrict__ psum, unsigned* __restrict__ pcnt,
    unsigned* __restrict__ counter, float* __restrict__ out) {
  const int row = blockIdx.x >> 4;          // /BPR
  const int blk = blockIdx.x & (BPR - 1);
  const size_t base = (size_t)row * NCOL + (size_t)blk * CHUNK;
  const float4* __restrict__ p4 = (const float4*)(pred + base) + threadIdx.x;
  const float4* __restrict__ t4 = (const float4*)(tgt + base) + threadIdx.x;

  // ---- deep-MLP load phase: 18 float4 loads in flight per wave ----
  float4 pv[ITERS], tv[ITERS];
#pragma unroll
  for (int j = 0; j < ITERS; ++j) {
    pv[j] = p4[(size_t)j * TPB];
    tv[j] = t4[(size_t)j * TPB];
  }

  float s0 = 0.f, s1 = 0.f, s2 = 0.f, s3 = 0.f;
  unsigned c = 0;
#pragma unroll
  for (int j = 0; j < ITERS; ++j) {
    const float4 p = pv[j], t = tv[j];
    const bool v0 = t.x > 0.f, v1 = t.y > 0.f, v2 = t.z > 0.f, v3 = t.w > 0.f;
    s0 += v0 ? fabsf(p.x - t.x) : 0.f;
    s1 += v1 ? fabsf(p.y - t.y) : 0.f;
    s2 += v2 ? fabsf(p.z - t.z) : 0.f;
    s3 += v3 ? fabsf(p.w - t.w) : 0.f;
    c += (unsigned)v0 + (unsigned)v1 + (unsigned)v2 + (unsigned)v3;
  }
  float s = (s0 + s1) + (s2 + s3);

  // ---- block reduce ----
  for (int off = 32; off > 0; off >>= 1) {
    s += __shfl_down(s, off, 64);
    c += __shfl_down(c, off, 64);
  }
  __shared__ float ss[4];
  __shared__ unsigned sc[4];
  const int wave = threadIdx.x >> 6, lane = threadIdx.x & 63;
  if (lane == 0) { ss[wave] = s; sc[wave] = c; }
  __syncthreads();

  __shared__ int is_last;
  if (threadIdx.x == 0) {
    float bs = ss[0] + ss[1] + ss[2] + ss[3];
    unsigned bc = sc[0] + sc[1] + sc[2] + sc[3];
    psum[blockIdx.x] = bs;
    pcnt[blockIdx.x] = bc;
    __threadfence();                       // make partials device-visible
    unsigned old = atomicAdd(counter, 1);  // device-scope
    is_last = (old == NBLK - 1);
  }
  __syncthreads();
  if (!is_last) return;
  __threadfence();                         // acquire all partials

  // =================== epilogue (one block) ===================
  __shared__ float row_loss[ROWS];
  __shared__ long long row_k[ROWS];
  __shared__ int row_flag[ROWS];
  __shared__ int any_flag;
  if (threadIdx.x == 0) any_flag = 0;
  __syncthreads();

  if (threadIdx.x < ROWS) {
    float rs = 0.f;
    unsigned rc = 0;
    for (int i = 0; i < BPR; ++i) {
      rs += psum[threadIdx.x * BPR + i];
      rc += pcnt[threadIdx.x * BPR + i];
    }
    const long long k = (long long)(NCOL - (long long)rc) + K0;
    if (k >= (long long)(NCOL - 1)) {
      // threshold = max residual -> trim removes nothing
      row_flag[threadIdx.x] = 0;
      row_loss[threadIdx.x] = (rc > 0) ? rs / (2.0f * (float)rc) : 0.f;
    } else {
      row_flag[threadIdx.x] = 1;
      row_k[threadIdx.x] = k;
      row_loss[threadIdx.x] = 0.f;
      atomicOr(&any_flag, 1);
    }
  }
  __syncthreads();

  if (any_flag) {
    // General-case safety net: exact k-th order statistic per flagged row
    // via 8-bit radix select on the nonneg-float bit pattern, then trimmed
    // sum. Cold path: not taken for this input distribution.
    __shared__ unsigned hist[256];
    __shared__ unsigned sh_sel;
    __shared__ long long sh_kk;
    for (int r = 0; r < ROWS; ++r) {
      if (!row_flag[r]) continue;
      const float* __restrict__ p = pred + (size_t)r * NCOL;
      const float* __restrict__ t = tgt + (size_t)r * NCOL;
      unsigned prefix = 0, prefmask = 0;
      long long kk = row_k[r];
      for (int shift = 24; shift >= 0; shift -= 8) {
        hist[threadIdx.x] = 0;
        __syncthreads();
        for (int i = threadIdx.x; i < NCOL; i += TPB) {
          const float ti = t[i];
          const float rr = (ti > 0.f) ? fabsf(p[i] - ti) : 0.f;
          const unsigned u = __float_as_uint(rr);
          if ((u & prefmask) == prefix) atomicAdd(&hist[(u >> shift) & 255u], 1u);
        }
        __syncthreads();
        if (threadIdx.x == 0) {
          long long cum = 0;
          unsigned sel = 255;
          for (int b = 0; b < 256; ++b) {
            const long long h = (long long)hist[b];
            if (kk < cum + h) { sel = (unsigned)b; break; }
            cum += h;
          }
          sh_sel = sel;
          sh_kk = kk - cum;
        }
        __syncthreads();
        prefix |= (sh_sel << shift);
        prefmask |= (255u << shift);
        kk = sh_kk;
        __syncthreads();
      }
      const float thresh = __uint_as_float(prefix);
      float ts = 0.f;
      unsigned tc = 0;
      for (int i = threadIdx.x; i < NCOL; i += TPB) {
        const float ti = t[i];
        const bool v = ti > 0.f;
        const float rr = v ? fabsf(p[i] - ti) : 0.f;
        if (rr <= thresh) ts += rr;
        tc += v;
      }
      for (int off = 32; off > 0; off >>= 1) {
        ts += __shfl_down(ts, off, 64);
        tc += __shfl_down(tc, off, 64);
      }
      if (lane == 0) { ss[wave] = ts; sc[wave] = tc; }
      __syncthreads();
      if (threadIdx.x == 0) {
        float fs = ss[0] + ss[1] + ss[2] + ss[3];
        unsigned fc = sc[0] + sc[1] + sc[2] + sc[3];
        row_loss[r] = (fc > 0) ? fs / (2.0f * (float)fc) : 0.f;
      }
      __syncthreads();
    }
  }
  __syncthreads();

  // ---- mean over rows ----
  float v = (threadIdx.x < ROWS) ? row_loss[threadIdx.x] : 0.f;
  for (int off = 32; off > 0; off >>= 1) v += __shfl_down(v, off, 64);
  if (lane == 0) ss[wave] = v;
  __syncthreads();
  if (threadIdx.x == 0)
    out[0] = (ss[0] + ss[1] + ss[2] + ss[3]) / (float)ROWS;
}

extern "C" void kernel_launch(void* const* d_in, const int* in_sizes, int n_in,
                              void* d_out, int out_size, void* d_ws, size_t ws_size,
                              hipStream_t stream) {
  const float* pred = (const float*)d_in[0];
  const float* tgt  = (const float*)d_in[1];
  float* out = (float*)d_out;

  char* ws = (char*)d_ws;
  float* psum    = (float*)ws;    ws += (size_t)NBLK * sizeof(float);
  unsigned* pcnt = (unsigned*)ws; ws += (size_t)NBLK * sizeof(unsigned);
  unsigned* counter = (unsigned*)ws;

  hipMemsetAsync(counter, 0, sizeof(unsigned), stream);  // graph-capture legal
  fused_kernel<<<NBLK, TPB, 0, stream>>>(pred, tgt, psum, pcnt, counter, out);
}

// Round 3
// 29.328 us; speedup vs baseline: 3.3092x; 3.3092x over previous
//
#include <hip/hip_runtime.h>

// Problem constants (B=128, H=W=384)
#define ROWS 128
#define NCOL 147456              // 384*384
#define BPR  16                  // blocks per row
#define TPB  256
#define CHUNK (NCOL / BPR)       // 9216 floats per block
#define N4    (CHUNK / 4)        // 2304 float4 per block  (9 per thread)
#define NBLK  (ROWS * BPR)       // 2048 blocks
static constexpr long long K0 = 117964;  // int((1.0 - 0.2) * NCOL)

#define ACC(p, t)                                            \
  do {                                                       \
    const bool v0 = (t).x > 0.f, v1 = (t).y > 0.f,           \
               v2 = (t).z > 0.f, v3 = (t).w > 0.f;           \
    s0 += v0 ? fabsf((p).x - (t).x) : 0.f;                   \
    s1 += v1 ? fabsf((p).y - (t).y) : 0.f;                   \
    s2 += v2 ? fabsf((p).z - (t).z) : 0.f;                   \
    s3 += v3 ? fabsf((p).w - (t).w) : 0.f;                   \
    c += (unsigned)v0 + (unsigned)v1 + (unsigned)v2 + (unsigned)v3; \
  } while (0)

// ---------------- Pass 1: per-(row,chunk) partial {sum(res), count(valid)} --
__global__ __launch_bounds__(TPB) void reduce_kernel(
    const float* __restrict__ pred, const float* __restrict__ tgt,
    float* __restrict__ psum, unsigned* __restrict__ pcnt) {
  const int row = blockIdx.x >> 4;          // /BPR
  const int blk = blockIdx.x & (BPR - 1);
  const size_t base = (size_t)row * NCOL + (size_t)blk * CHUNK;
  const float4* __restrict__ p4 = (const float4*)(pred + base);
  const float4* __restrict__ t4 = (const float4*)(tgt + base);

  float s0 = 0.f, s1 = 0.f, s2 = 0.f, s3 = 0.f;
  unsigned c = 0;

  // 9 float4-pairs per thread: 4 double-steps (2 pairs in flight) + 1 tail.
  int i = threadIdx.x;
#pragma unroll
  for (int jj = 0; jj < 4; ++jj) {
    const float4 pa = p4[i];
    const float4 ta = t4[i];
    const float4 pb = p4[i + TPB];
    const float4 tb = t4[i + TPB];
    ACC(pa, ta);
    ACC(pb, tb);
    i += 2 * TPB;
  }
  {
    const float4 pa = p4[i];
    const float4 ta = t4[i];
    ACC(pa, ta);
  }
  float s = (s0 + s1) + (s2 + s3);

  // wave64 shuffle reduce, then 4 waves via LDS
  for (int off = 32; off > 0; off >>= 1) {
    s += __shfl_down(s, off, 64);
    c += __shfl_down(c, off, 64);
  }
  __shared__ float ss[4];
  __shared__ unsigned sc[4];
  const int wave = threadIdx.x >> 6, lane = threadIdx.x & 63;
  if (lane == 0) { ss[wave] = s; sc[wave] = c; }
  __syncthreads();
  if (threadIdx.x == 0) {
    psum[blockIdx.x] = ss[0] + ss[1] + ss[2] + ss[3];
    pcnt[blockIdx.x] = sc[0] + sc[1] + sc[2] + sc[3];
  }
}

// ---------------- Pass 2 (single block): row stats + cold trim + mean ------
__global__ __launch_bounds__(TPB) void finalize_kernel(
    const float* __restrict__ pred, const float* __restrict__ tgt,
    const float* __restrict__ psum, const unsigned* __restrict__ pcnt,
    float* __restrict__ out) {
  __shared__ float row_loss[ROWS];
  __shared__ long long row_k[ROWS];
  __shared__ int row_flag[ROWS];
  __shared__ int any_flag;
  __shared__ float ss[4];
  __shared__ unsigned sc[4];
  const int wave = threadIdx.x >> 6, lane = threadIdx.x & 63;

  if (threadIdx.x == 0) any_flag = 0;
  __syncthreads();

  if (threadIdx.x < ROWS) {
    float rs = 0.f;
    unsigned rc = 0;
    for (int i = 0; i < BPR; ++i) {
      rs += psum[threadIdx.x * BPR + i];
      rc += pcnt[threadIdx.x * BPR + i];
    }
    const long long k = (long long)(NCOL - (long long)rc) + K0;  // pre-clip
    if (k >= (long long)(NCOL - 1)) {
      // threshold clips to the max residual -> trim removes nothing
      row_flag[threadIdx.x] = 0;
      row_loss[threadIdx.x] = (rc > 0) ? rs / (2.0f * (float)rc) : 0.f;
    } else {
      row_flag[threadIdx.x] = 1;
      row_k[threadIdx.x] = k;
      row_loss[threadIdx.x] = 0.f;
      atomicOr(&any_flag, 1);
    }
  }
  __syncthreads();

  if (any_flag) {
    // General-case safety net (cold for this input distribution): exact k-th
    // order statistic via 8-bit radix select on nonneg-float bits + trimmed sum.
    __shared__ unsigned hist[256];
    __shared__ unsigned sh_sel;
    __shared__ long long sh_kk;
    for (int r = 0; r < ROWS; ++r) {
      if (!row_flag[r]) continue;
      const float* __restrict__ p = pred + (size_t)r * NCOL;
      const float* __restrict__ t = tgt + (size_t)r * NCOL;
      unsigned prefix = 0, prefmask = 0;
      long long kk = row_k[r];
      for (int shift = 24; shift >= 0; shift -= 8) {
        hist[threadIdx.x] = 0;
        __syncthreads();
        for (int i = threadIdx.x; i < NCOL; i += TPB) {
          const float ti = t[i];
          const float rr = (ti > 0.f) ? fabsf(p[i] - ti) : 0.f;
          const unsigned u = __float_as_uint(rr);
          if ((u & prefmask) == prefix) atomicAdd(&hist[(u >> shift) & 255u], 1u);
        }
        __syncthreads();
        if (threadIdx.x == 0) {
          long long cum = 0;
          unsigned sel = 255;
          for (int b = 0; b < 256; ++b) {
            const long long h = (long long)hist[b];
            if (kk < cum + h) { sel = (unsigned)b; break; }
            cum += h;
          }
          sh_sel = sel;
          sh_kk = kk - cum;
        }
        __syncthreads();
        prefix |= (sh_sel << shift);
        prefmask |= (255u << shift);
        kk = sh_kk;
        __syncthreads();
      }
      const float thresh = __uint_as_float(prefix);
      float ts = 0.f;
      unsigned tc = 0;
      for (int i = threadIdx.x; i < NCOL; i += TPB) {
        const float ti = t[i];
        const bool v = ti > 0.f;
        const float rr = v ? fabsf(p[i] - ti) : 0.f;
        if (rr <= thresh) ts += rr;
        tc += v;
      }
      for (int off = 32; off > 0; off >>= 1) {
        ts += __shfl_down(ts, off, 64);
        tc += __shfl_down(tc, off, 64);
      }
      if (lane == 0) { ss[wave] = ts; sc[wave] = tc; }
      __syncthreads();
      if (threadIdx.x == 0) {
        const float fs = ss[0] + ss[1] + ss[2] + ss[3];
        const unsigned fc = sc[0] + sc[1] + sc[2] + sc[3];
        row_loss[r] = (fc > 0) ? fs / (2.0f * (float)fc) : 0.f;
      }
      __syncthreads();
    }
  }
  __syncthreads();

  // mean over rows
  float v = (threadIdx.x < ROWS) ? row_loss[threadIdx.x] : 0.f;
  for (int off = 32; off > 0; off >>= 1) v += __shfl_down(v, off, 64);
  if (lane == 0) ss[wave] = v;
  __syncthreads();
  if (threadIdx.x == 0)
    out[0] = (ss[0] + ss[1] + ss[2] + ss[3]) / (float)ROWS;
}

extern "C" void kernel_launch(void* const* d_in, const int* in_sizes, int n_in,
                              void* d_out, int out_size, void* d_ws, size_t ws_size,
                              hipStream_t stream) {
  const float* pred = (const float*)d_in[0];
  const float* tgt  = (const float*)d_in[1];
  float* out = (float*)d_out;

  char* ws = (char*)d_ws;
  float* psum    = (float*)ws;    ws += (size_t)NBLK * sizeof(float);
  unsigned* pcnt = (unsigned*)ws;

  reduce_kernel<<<NBLK, TPB, 0, stream>>>(pred, tgt, psum, pcnt);
  finalize_kernel<<<1, TPB, 0, stream>>>(pred, tgt, psum, pcnt, out);
}